// Round 3
// baseline (4891.064 us; speedup 1.0000x reference)
//
#include <hip/hip_runtime.h>
#include <hip/hip_fp16.h>

typedef _Float16 f16;
typedef _Float16 f16x2 __attribute__((ext_vector_type(2)));
typedef unsigned short u16;
typedef unsigned int u32;

__device__ __forceinline__ float fdot2v(f16x2 a, f16x2 b, float c){
#if __has_builtin(__builtin_amdgcn_fdot2)
  return __builtin_amdgcn_fdot2(a, b, c, false);
#else
  return c + (float)a.x * (float)b.x + (float)a.y * (float)b.y;
#endif
}

__device__ __forceinline__ float tanh_f(float x){
  // 1 - 2/(e^{2x}+1); exp overflow/underflow saturate correctly to +-1
  return 1.f - 2.f / (__expf(2.f * x) + 1.f);
}
__device__ __forceinline__ float sigm_f(float x){
  return 1.f / (1.f + __expf(-x));
}
__device__ __forceinline__ float leaky_f(float x){
  return x >= 0.f ? x : x * (1.0f / 5.5f);
}

// Load NP f32 pairs from row-major W[row][c0 + 2p (+1)] into f16x2 regs,
// zero-padding out-of-range columns. Row forced safe by caller when !valid.
template<int NP>
__device__ __forceinline__ void ld_pairs(const float* W, int row, int ncols, int c0,
                                         f16x2* dst, bool valid){
  const float* base = W + (long)row * ncols;
#pragma unroll
  for (int p = 0; p < NP; p++){
    int c = c0 + 2 * p;
    f16x2 v;
    v.x = (valid && c     < ncols) ? (f16)base[c]     : (f16)0.f;
    v.y = (valid && c + 1 < ncols) ? (f16)base[c + 1] : (f16)0.f;
    dst[p] = v;
  }
}

// Field MLP weights, per-thread register fragments.
// Mapping (tid in [0,512)):
//  stage1/2 pass1: output j1 = tid>>1, K-half h = tid&1
//  stage1/2 pass2: outputs 256..274, 16-way K-split (tid<304, m=tid>>4, s=tid&15)
//  stage3:         output j3 = tid>>2 (<100), K-quarter q = tid&3
struct FR {
  f16x2 w1[25]; float w1t;  float b1;
  f16x2 w1b[4]; float w1tb; float b1b;
  f16x2 w2[69]; float b2;
  f16x2 w2b[9]; float b2b;
  f16x2 w3[35]; float b3;
};

__device__ __forceinline__ void load_field_regs(FR& R, int tid,
    const float* fW1, const float* fb1, const float* fW2, const float* fb2,
    const float* fW3, const float* fb3)
{
  int j1 = tid >> 1, h = tid & 1;
  ld_pairs<25>(fW1, j1, 101, 1 + 50 * h, R.w1, true);
  R.w1t = h ? 0.f : fW1[j1 * 101];
  R.b1  = fb1[j1];
  ld_pairs<69>(fW2, j1, 275, 138 * h, R.w2, true);
  R.b2  = fb2[j1];
  bool p2 = tid < 304;
  int m = tid >> 4, s = tid & 15;
  int j2 = 256 + m;
  ld_pairs<4>(fW1, p2 ? j2 : 0, 101, 1 + 8 * s, R.w1b, p2);
  R.w1tb = (p2 && s == 0) ? fW1[j2 * 101] : 0.f;
  R.b1b  = p2 ? fb1[j2] : 0.f;
  ld_pairs<9>(fW2, p2 ? j2 : 0, 275, 18 * s, R.w2b, p2);
  R.b2b  = p2 ? fb2[j2] : 0.f;
  int j3 = tid >> 2, q = tid & 3;
  bool v3 = j3 < 100;
  ld_pairs<35>(fW3, v3 ? j3 : 0, 275, 70 * q, R.w3, v3);
  R.b3 = v3 ? fb3[j3] : 0.f;
}

// One field evaluation. On entry: yst2 holds x_in y-part (f16, pads zero) and a
// barrier has been passed. Returns pre-tanh stage3 value; valid for writer
// threads (tid&3)==0 && (tid>>2)<100. Contains 2 internal barriers.
__device__ __forceinline__ float field_eval(const FR& R, float t, int tid,
    const f16x2* yst2, f16* x1s, f16* x2s)
{
  const f16x2* x1v = (const f16x2*)x1s;
  const f16x2* x2v = (const f16x2*)x2s;
  int j1 = tid >> 1, h = tid & 1;
  // ---- stage 1: x1 = tanh([t,y] @ fW1^T + fb1), N=275, K=101 ----
  {
    float a = h ? 0.f : R.w1t * t;
    const f16x2* yv = yst2 + 25 * h;
#pragma unroll
    for (int p = 0; p < 25; p++) a = fdot2v(R.w1[p], yv[p], a);
    a += __shfl_xor(a, 1);
    if (!h) x1s[j1] = (f16)tanh_f(a + R.b1);
    if (tid < 304){
      int s = tid & 15;
      float a2 = (s == 0) ? R.w1tb * t : 0.f;
      const f16x2* yv2 = yst2 + 4 * s;
#pragma unroll
      for (int p = 0; p < 4; p++) a2 = fdot2v(R.w1b[p], yv2[p], a2);
      a2 += __shfl_xor(a2, 1); a2 += __shfl_xor(a2, 2);
      a2 += __shfl_xor(a2, 4); a2 += __shfl_xor(a2, 8);
      if (s == 0) x1s[256 + (tid >> 4)] = (f16)tanh_f(a2 + R.b1b);
    }
  }
  __syncthreads();
  // ---- stage 2: x2 = tanh(x1 @ fW2^T + fb2), N=275, K=275 ----
  {
    float a = 0.f;
    const f16x2* xv = x1v + 69 * h;
#pragma unroll
    for (int p = 0; p < 69; p++) a = fdot2v(R.w2[p], xv[p], a);
    a += __shfl_xor(a, 1);
    if (!h) x2s[j1] = (f16)tanh_f(a + R.b2);
    if (tid < 304){
      int s = tid & 15;
      float a2 = 0.f;
      const f16x2* xv2 = x1v + 9 * s;
#pragma unroll
      for (int p = 0; p < 9; p++) a2 = fdot2v(R.w2b[p], xv2[p], a2);
      a2 += __shfl_xor(a2, 1); a2 += __shfl_xor(a2, 2);
      a2 += __shfl_xor(a2, 4); a2 += __shfl_xor(a2, 8);
      if (s == 0) x2s[256 + (tid >> 4)] = (f16)tanh_f(a2 + R.b2b);
    }
  }
  __syncthreads();
  // ---- stage 3: f = tanh(x2 @ fW3^T + fb3), N=100, K=275 ----
  float a = 0.f;
  {
    int q = tid & 3;
    const f16x2* xv = x2v + 35 * q;
#pragma unroll
    for (int p = 0; p < 35; p++) a = fdot2v(R.w3[p], xv[p], a);
    a += __shfl_xor(a, 1); a += __shfl_xor(a, 2);
  }
  return a + R.b3;
}

// ===================== Kernel 1: encoder + latent MLP =====================
__global__ __launch_bounds__(512) void k_encode(
    const float* __restrict__ past, const float* __restrict__ h0,
    const float* __restrict__ fW1, const float* __restrict__ fb1,
    const float* __restrict__ fW2, const float* __restrict__ fb2,
    const float* __restrict__ fW3, const float* __restrict__ fb3,
    const float* __restrict__ Wih, const float* __restrict__ Whh,
    const float* __restrict__ bih, const float* __restrict__ bhh,
    const float* __restrict__ gW1, const float* __restrict__ gb1,
    const float* __restrict__ gW2, const float* __restrict__ gb2,
    const float* __restrict__ gW3, const float* __restrict__ gb3,
    float* __restrict__ gx_ws)
{
  __shared__ f16x2 yst2[64];     // staged y (f16), pads zero
  __shared__ f16x2 x1s2[144];    // 288 f16, pads zero
  __shared__ f16x2 x2s2[144];
  __shared__ float yf[100];      // fp32 master state
  __shared__ float ghs[300];
  __shared__ f16x2 gW1s[75 * 52];
  __shared__ f16x2 gW2s[75 * 40];
  __shared__ f16x2 gW3s[80];
  __shared__ f16x2 g1s2[40];
  __shared__ f16x2 g2s2[40];

  const int tid = threadIdx.x;
  const int b = blockIdx.x;
  f16* yst = (f16*)yst2;
  f16* x1s = (f16*)x1s2;
  f16* x2s = (f16*)x2s2;
  f16* g1s = (f16*)g1s2;
  f16* g2s = (f16*)g2s2;

  FR R;
  load_field_regs(R, tid, fW1, fb1, fW2, fb2, fW3, fb3);

  // GRU hidden-hidden weights: pass1 rows 0..255 (2-way K), pass2 rows 256..299 (8-way K)
  f16x2 whh[25]; float bhhv;
  f16x2 whhb[7]; float bhhbv;
  {
    int j1 = tid >> 1, h = tid & 1;
    ld_pairs<25>(Whh, j1, 100, 50 * h, whh, true);
    bhhv = bhh[j1];
    bool p2 = tid < 352;
    int j2 = 256 + (tid >> 3), s7 = tid & 7;
    ld_pairs<7>(Whh, p2 ? j2 : 0, 100, 14 * s7, whhb, p2);
    bhhbv = p2 ? bhh[j2] : 0.f;
  }
  float wihr=0,wihz=0,wihn=0,bihr=0,bihz=0,bihn=0;
  if (tid < 100){
    wihr = Wih[tid];       bihr = bih[tid];
    wihz = Wih[tid + 100]; bihz = bih[tid + 100];
    wihn = Wih[tid + 200]; bihn = bih[tid + 200];
  }
  const int jq = tid >> 2, qq = tid & 3;
  const bool lv = (qq == 0 && jq < 75);
  float gb1v = lv ? gb1[jq] : 0.f;
  float gb2v = lv ? gb2[jq] : 0.f;

  // latent weights -> LDS (f16, padded strides)
  for (int i = tid; i < 75 * 52; i += 512){
    int r = i / 52, c = 2 * (i % 52);
    f16x2 v;
    v.x = (c     < 100) ? (f16)gW1[r * 100 + c]     : (f16)0.f;
    v.y = (c + 1 < 100) ? (f16)gW1[r * 100 + c + 1] : (f16)0.f;
    gW1s[i] = v;
  }
  for (int i = tid; i < 75 * 40; i += 512){
    int r = i / 40, c = 2 * (i % 40);
    f16x2 v;
    v.x = (c     < 75) ? (f16)gW2[r * 75 + c]     : (f16)0.f;
    v.y = (c + 1 < 75) ? (f16)gW2[r * 75 + c + 1] : (f16)0.f;
    gW2s[i] = v;
  }
  for (int i = tid; i < 80; i += 512){
    int r = i / 40, c = 2 * (i % 40);
    f16x2 v;
    v.x = (c     < 75) ? (f16)gW3[r * 75 + c]     : (f16)0.f;
    v.y = (c + 1 < 75) ? (f16)gW3[r * 75 + c + 1] : (f16)0.f;
    gW3s[i] = v;
  }
  // staging init (pads must be zero)
  for (int i = tid; i < 128; i += 512) yst[i] = (f16)0.f;
  for (int i = tid; i < 288; i += 512){ x1s[i] = (f16)0.f; x2s[i] = (f16)0.f; }
  for (int i = tid; i < 80;  i += 512){ g1s[i] = (f16)0.f; g2s[i] = (f16)0.f; }
  if (tid < 100){ float v = h0[b * 100 + tid]; yf[tid] = v; yst[tid] = (f16)v; }
  __syncthreads();

  const int j3 = tid >> 2;
  const bool wr3 = ((tid & 3) == 0) && (j3 < 100);
  float k1v = 0.f, k2v = 0.f, k3v = 0.f;

  auto rk_interval = [&](float tp, float tc){
    float dts = (tc - tp) * 0.5f;   // (t1-t0)/NSUB
#pragma unroll 1
    for (int sub = 0; sub < 2; sub++){
      float t0 = tp + sub * dts;
      __syncthreads();
      float a = field_eval(R, t0, tid, yst2, x1s, x2s);
      if (wr3){ float kv = tanh_f(a); k1v = kv; yst[j3] = (f16)(yf[j3] + 0.5f * dts * kv); }
      __syncthreads();
      a = field_eval(R, t0 + 0.5f * dts, tid, yst2, x1s, x2s);
      if (wr3){ float kv = tanh_f(a); k2v = kv; yst[j3] = (f16)(yf[j3] + 0.5f * dts * kv); }
      __syncthreads();
      a = field_eval(R, t0 + 0.5f * dts, tid, yst2, x1s, x2s);
      if (wr3){ float kv = tanh_f(a); k3v = kv; yst[j3] = (f16)(yf[j3] + dts * kv); }
      __syncthreads();
      a = field_eval(R, t0 + dts, tid, yst2, x1s, x2s);
      if (wr3){
        float kv = tanh_f(a);
        float yn = yf[j3] + dts * (k1v + 2.f * (k2v + k3v) + kv) * (1.f / 6.f);
        yf[j3] = yn; yst[j3] = (f16)yn;
      }
    }
  };

  const float* prow = past + b * 64;  // (32 steps) x [t, x]
#pragma unroll 1
  for (int st = 0; st < 32; st++){
    float tc = prow[2 * st];
    float tp = (st == 0) ? (tc - 1.f) : prow[2 * st - 2];
    rk_interval(tp, tc);
    // ---- GRU update ----
    __syncthreads();   // yst = integrated h ready
    {
      int j1 = tid >> 1, h = tid & 1;
      float a = 0.f;
      const f16x2* yv = yst2 + 25 * h;
#pragma unroll
      for (int p = 0; p < 25; p++) a = fdot2v(whh[p], yv[p], a);
      a += __shfl_xor(a, 1);
      if (!h) ghs[j1] = a + bhhv;
      if (tid < 352){
        int s7 = tid & 7;
        float a2 = 0.f;
        const f16x2* yv2 = yst2 + 7 * s7;
#pragma unroll
        for (int p = 0; p < 7; p++) a2 = fdot2v(whhb[p], yv2[p], a2);
        a2 += __shfl_xor(a2, 1); a2 += __shfl_xor(a2, 2); a2 += __shfl_xor(a2, 4);
        if (s7 == 0) ghs[256 + (tid >> 3)] = a2 + bhhbv;
      }
    }
    __syncthreads();
    if (tid < 100){
      float x = prow[2 * st + 1];
      float r = sigm_f(x * wihr + bihr + ghs[tid]);
      float z = sigm_f(x * wihz + bihz + ghs[tid + 100]);
      float n = tanh_f(x * wihn + bihn + r * ghs[tid + 200]);
      float hn = (1.f - z) * n + z * yf[tid];
      yf[tid] = hn; yst[tid] = (f16)hn;
    }
  }

  // ---- latent MLP: gx = (leaky,leaky,linear)(h) ----
  __syncthreads();
  {
    float a = 0.f;
    const f16x2* yv = yst2 + 13 * qq;
    if (jq < 75){
#pragma unroll
      for (int p = 0; p < 13; p++) a = fdot2v(gW1s[jq * 52 + 13 * qq + p], yv[p], a);
    }
    a += __shfl_xor(a, 1); a += __shfl_xor(a, 2);
    if (lv) g1s[jq] = (f16)leaky_f(a + gb1v);
  }
  __syncthreads();
  {
    float a = 0.f;
    const f16x2* xv = (const f16x2*)g1s + 10 * qq;
    if (jq < 75){
#pragma unroll
      for (int p = 0; p < 10; p++) a = fdot2v(gW2s[jq * 40 + 10 * qq + p], xv[p], a);
    }
    a += __shfl_xor(a, 1); a += __shfl_xor(a, 2);
    if (lv) g2s[jq] = (f16)leaky_f(a + gb2v);
  }
  __syncthreads();
  if (tid < 2){
    const f16x2* g2v = (const f16x2*)g2s;
    float a = gb3[tid];
    for (int p = 0; p < 40; p++) a = fdot2v(gW3s[tid * 40 + p], g2v[p], a);
    gx_ws[b * 2 + tid] = a;
  }
}

// ===================== Kernel 2: z0 + forecast ODE + decoder =====================
__global__ __launch_bounds__(512) void k_forecast(
    const float* __restrict__ t_future, const float* __restrict__ eps,
    const float* __restrict__ fW1, const float* __restrict__ fb1,
    const float* __restrict__ fW2, const float* __restrict__ fb2,
    const float* __restrict__ fW3, const float* __restrict__ fb3,
    const float* __restrict__ oW1, const float* __restrict__ ob1,
    const float* __restrict__ oW2, const float* __restrict__ ob2,
    const float* __restrict__ oW3, const float* __restrict__ ob3,
    const float* __restrict__ gx_ws, float* __restrict__ out)
{
  __shared__ f16x2 yst2[64];
  __shared__ f16x2 x1s2[144];
  __shared__ f16x2 x2s2[144];
  __shared__ float yf[100];
  __shared__ f16x2 oW1s[75 * 52];
  __shared__ f16x2 oW2s[75 * 40];
  __shared__ f16x2 oW3s[40];
  __shared__ f16x2 o1s2[40];
  __shared__ f16x2 o2s2[40];

  const int tid = threadIdx.x;
  const int b = blockIdx.x;
  f16* yst = (f16*)yst2;
  f16* x1s = (f16*)x1s2;
  f16* x2s = (f16*)x2s2;
  f16* o1s = (f16*)o1s2;
  f16* o2s = (f16*)o2s2;

  FR R;
  load_field_regs(R, tid, fW1, fb1, fW2, fb2, fW3, fb3);

  const int jq = tid >> 2, qq = tid & 3;
  const bool lv = (qq == 0 && jq < 75);
  float ob1v = lv ? ob1[jq] : 0.f;
  float ob2v = lv ? ob2[jq] : 0.f;
  float ob3v = ob3[0];

  for (int i = tid; i < 75 * 52; i += 512){
    int r = i / 52, c = 2 * (i % 52);
    f16x2 v;
    v.x = (c     < 100) ? (f16)oW1[r * 100 + c]     : (f16)0.f;
    v.y = (c + 1 < 100) ? (f16)oW1[r * 100 + c + 1] : (f16)0.f;
    oW1s[i] = v;
  }
  for (int i = tid; i < 75 * 40; i += 512){
    int r = i / 40, c = 2 * (i % 40);
    f16x2 v;
    v.x = (c     < 75) ? (f16)oW2[r * 75 + c]     : (f16)0.f;
    v.y = (c + 1 < 75) ? (f16)oW2[r * 75 + c + 1] : (f16)0.f;
    oW2s[i] = v;
  }
  for (int i = tid; i < 40; i += 512){
    int c = 2 * i;
    f16x2 v;
    v.x = (c     < 75) ? (f16)oW3[c]     : (f16)0.f;
    v.y = (c + 1 < 75) ? (f16)oW3[c + 1] : (f16)0.f;
    oW3s[i] = v;
  }
  for (int i = tid; i < 128; i += 512) yst[i] = (f16)0.f;
  for (int i = tid; i < 288; i += 512){ x1s[i] = (f16)0.f; x2s[i] = (f16)0.f; }
  for (int i = tid; i < 80;  i += 512){ o1s[i] = (f16)0.f; o2s[i] = (f16)0.f; }
  // z0 = loc + scale * eps  (pr reshuffle across rows via gx_ws)
  if (tid < 100){
    float loc, scl;
    if (b < 128){ loc = gx_ws[4 * b];          scl = gx_ws[4 * b + 2]; }
    else        { loc = fabsf(gx_ws[4 * b - 511]); scl = fabsf(gx_ws[4 * b - 509]); }
    float e = eps[tid * 256 + b];
    float v0 = loc + scl * e;
    yf[tid] = v0; yst[tid] = (f16)v0;
  }
  __syncthreads();

  auto decode = [&](int tf){
    // assumes a barrier has been passed and yst holds current y
    {
      float a = 0.f;
      const f16x2* yv = yst2 + 13 * qq;
      if (jq < 75){
#pragma unroll
        for (int p = 0; p < 13; p++) a = fdot2v(oW1s[jq * 52 + 13 * qq + p], yv[p], a);
      }
      a += __shfl_xor(a, 1); a += __shfl_xor(a, 2);
      if (lv) o1s[jq] = (f16)leaky_f(a + ob1v);
    }
    __syncthreads();
    {
      float a = 0.f;
      const f16x2* xv = (const f16x2*)o1s + 10 * qq;
      if (jq < 75){
#pragma unroll
        for (int p = 0; p < 10; p++) a = fdot2v(oW2s[jq * 40 + 10 * qq + p], xv[p], a);
      }
      a += __shfl_xor(a, 1); a += __shfl_xor(a, 2);
      if (lv) o2s[jq] = (f16)leaky_f(a + ob2v);
    }
    __syncthreads();
    if (tid < 64){
      float a = 0.f;
      if (tid < 40) a = fdot2v(oW3s[tid], ((const f16x2*)o2s)[tid], 0.f);
      a += __shfl_xor(a, 1);  a += __shfl_xor(a, 2);  a += __shfl_xor(a, 4);
      a += __shfl_xor(a, 8);  a += __shfl_xor(a, 16); a += __shfl_xor(a, 32);
      if (tid == 0) out[b * 256 + tf] = a + ob3v;
    }
  };

  decode(0);

  const float* trow = t_future + b * 256;
  const int j3 = tid >> 2;
  const bool wr3 = ((tid & 3) == 0) && (j3 < 100);
  float k1v = 0.f, k2v = 0.f, k3v = 0.f;

#pragma unroll 1
  for (int iv = 0; iv < 255; iv++){
    float tp = trow[iv];
    float tc = trow[iv + 1];
    float dts = (tc - tp) * 0.5f;
#pragma unroll 1
    for (int sub = 0; sub < 2; sub++){
      float t0 = tp + sub * dts;
      __syncthreads();
      float a = field_eval(R, t0, tid, yst2, x1s, x2s);
      if (wr3){ float kv = tanh_f(a); k1v = kv; yst[j3] = (f16)(yf[j3] + 0.5f * dts * kv); }
      __syncthreads();
      a = field_eval(R, t0 + 0.5f * dts, tid, yst2, x1s, x2s);
      if (wr3){ float kv = tanh_f(a); k2v = kv; yst[j3] = (f16)(yf[j3] + 0.5f * dts * kv); }
      __syncthreads();
      a = field_eval(R, t0 + 0.5f * dts, tid, yst2, x1s, x2s);
      if (wr3){ float kv = tanh_f(a); k3v = kv; yst[j3] = (f16)(yf[j3] + dts * kv); }
      __syncthreads();
      a = field_eval(R, t0 + dts, tid, yst2, x1s, x2s);
      if (wr3){
        float kv = tanh_f(a);
        float yn = yf[j3] + dts * (k1v + 2.f * (k2v + k3v) + kv) * (1.f / 6.f);
        yf[j3] = yn; yst[j3] = (f16)yn;
      }
    }
    __syncthreads();   // yst ready for decoder
    decode(iv + 1);
  }
}

extern "C" void kernel_launch(void* const* d_in, const int* in_sizes, int n_in,
                              void* d_out, int out_size, void* d_ws, size_t ws_size,
                              hipStream_t stream) {
  (void)in_sizes; (void)n_in; (void)out_size; (void)ws_size;
  const float* past     = (const float*)d_in[0];
  const float* h0       = (const float*)d_in[1];
  const float* t_future = (const float*)d_in[2];
  const float* eps      = (const float*)d_in[3];
  const float* fW1 = (const float*)d_in[4];  const float* fb1 = (const float*)d_in[5];
  const float* fW2 = (const float*)d_in[6];  const float* fb2 = (const float*)d_in[7];
  const float* fW3 = (const float*)d_in[8];  const float* fb3 = (const float*)d_in[9];
  const float* Wih = (const float*)d_in[10]; const float* Whh = (const float*)d_in[11];
  const float* bih = (const float*)d_in[12]; const float* bhh = (const float*)d_in[13];
  const float* gW1 = (const float*)d_in[14]; const float* gb1 = (const float*)d_in[15];
  const float* gW2 = (const float*)d_in[16]; const float* gb2 = (const float*)d_in[17];
  const float* gW3 = (const float*)d_in[18]; const float* gb3 = (const float*)d_in[19];
  const float* oW1 = (const float*)d_in[20]; const float* ob1 = (const float*)d_in[21];
  const float* oW2 = (const float*)d_in[22]; const float* ob2 = (const float*)d_in[23];
  const float* oW3 = (const float*)d_in[24]; const float* ob3 = (const float*)d_in[25];
  float* gxws = (float*)d_ws;
  float* out = (float*)d_out;

  hipLaunchKernelGGL(k_encode, dim3(256), dim3(512), 0, stream,
      past, h0, fW1, fb1, fW2, fb2, fW3, fb3,
      Wih, Whh, bih, bhh, gW1, gb1, gW2, gb2, gW3, gb3, gxws);
  hipLaunchKernelGGL(k_forecast, dim3(256), dim3(512), 0, stream,
      t_future, eps, fW1, fb1, fW2, fb2, fW3, fb3,
      oW1, ob1, oW2, ob2, oW3, ob3, gxws, out);
}

// Round 4
// 4681.292 us; speedup vs baseline: 1.0448x; 1.0448x over previous
//
#include <hip/hip_runtime.h>
#include <hip/hip_fp16.h>

typedef _Float16 f16;
typedef _Float16 f16x2 __attribute__((ext_vector_type(2)));
typedef _Float16 f16x8 __attribute__((ext_vector_type(8)));
typedef unsigned short u16;
typedef unsigned int u32;

__device__ __forceinline__ float fdot2v(f16x2 a, f16x2 b, float c){
#if __has_builtin(__builtin_amdgcn_fdot2)
  return __builtin_amdgcn_fdot2(a, b, c, false);
#else
  return c + (float)a.x * (float)b.x + (float)a.y * (float)b.y;
#endif
}

__device__ __forceinline__ float tanh_f(float x){
  return 1.f - 2.f / (__expf(2.f * x) + 1.f);
}
__device__ __forceinline__ float sigm_f(float x){
  return 1.f / (1.f + __expf(-x));
}
__device__ __forceinline__ float leaky_f(float x){
  return x >= 0.f ? x : x * (1.0f / 5.5f);
}

// Load NP f32 pairs from row-major W[row][c0 + 2p (+1)] into f16x2 regs,
// zero-padding out-of-range columns. Row forced safe by caller when !valid.
template<int NP>
__device__ __forceinline__ void ld_pairs(const float* W, int row, int ncols, int c0,
                                         f16x2* dst, bool valid){
  const float* base = W + (long)row * ncols;
#pragma unroll
  for (int p = 0; p < NP; p++){
    int c = c0 + 2 * p;
    f16x2 v;
    v.x = (valid && c     < ncols) ? (f16)base[c]     : (f16)0.f;
    v.y = (valid && c + 1 < ncols) ? (f16)base[c + 1] : (f16)0.f;
    dst[p] = v;
  }
}

// Dot of NCH f16x8 LDS chunks (b128 reads, broadcast addresses) against
// register weights w[4*NCH] (f16x2), 4 accumulators to break dep chains.
template<int NCH>
__device__ __forceinline__ float dot_chunks(const f16x2* w, const f16x8* x, int chunk0){
  float a0 = 0.f, a1 = 0.f, a2 = 0.f, a3 = 0.f;
#pragma unroll
  for (int c = 0; c < NCH; c++){
    union { f16x8 v; f16x2 h[4]; } u;
    u.v = x[chunk0 + c];
    a0 = fdot2v(w[4*c + 0], u.h[0], a0);
    a1 = fdot2v(w[4*c + 1], u.h[1], a1);
    a2 = fdot2v(w[4*c + 2], u.h[2], a2);
    a3 = fdot2v(w[4*c + 3], u.h[3], a3);
  }
  return (a0 + a1) + (a2 + a3);
}

// Field MLP weights, per-thread register fragments. 16B-aligned K-splits:
//  stage1 pass1: j1=tid>>1, half h=tid&1: elements 56h..56h+55 of y (col = el+1)
//  stage2 pass1: elements 144h..144h+143 of x1
//  stage1/2 pass2: rows 256..274, 16-way f16x2 K-split (tid<304)
//  stage3: j3=tid>>2 (<100), quarter q: elements 72q..72q+71 of x2
struct FR {
  f16x2 w1[28]; float w1t;  float b1;
  f16x2 w1b[4]; float w1tb; float b1b;
  f16x2 w2[72]; float b2;
  f16x2 w2b[9]; float b2b;
  f16x2 w3[36]; float b3;
};

__device__ __forceinline__ void load_field_regs(FR& R, int tid,
    const float* fW1, const float* fb1, const float* fW2, const float* fb2,
    const float* fW3, const float* fb3)
{
  int j1 = tid >> 1, h = tid & 1;
  ld_pairs<28>(fW1, j1, 101, 1 + 56 * h, R.w1, true);
  R.w1t = h ? 0.f : fW1[j1 * 101];
  R.b1  = fb1[j1];
  ld_pairs<72>(fW2, j1, 275, 144 * h, R.w2, true);
  R.b2  = fb2[j1];
  bool p2 = tid < 304;
  int m = tid >> 4, s = tid & 15;
  int j2 = 256 + m;
  ld_pairs<4>(fW1, p2 ? j2 : 0, 101, 1 + 8 * s, R.w1b, p2);
  R.w1tb = (p2 && s == 0) ? fW1[j2 * 101] : 0.f;
  R.b1b  = p2 ? fb1[j2] : 0.f;
  ld_pairs<9>(fW2, p2 ? j2 : 0, 275, 18 * s, R.w2b, p2);
  R.b2b  = p2 ? fb2[j2] : 0.f;
  int j3 = tid >> 2, q = tid & 3;
  bool v3 = j3 < 100;
  ld_pairs<36>(fW3, v3 ? j3 : 0, 275, 72 * q, R.w3, v3);
  R.b3 = v3 ? fb3[j3] : 0.f;
}

// One field evaluation. yst: 16 chunks (128 f16: y[0..99], pads 0).
// x1/x2: 36 chunks (288 f16, pads 0). 2 internal barriers.
__device__ __forceinline__ float field_eval(const FR& R, float t, int tid,
    const f16x8* ystV, const f16x8* x1V, const f16x8* x2V,
    f16* x1s, f16* x2s)
{
  int j1 = tid >> 1, h = tid & 1;
  // ---- stage 1: x1 = tanh([t,y] @ fW1^T + fb1), N=275, K=101 ----
  {
    float a = dot_chunks<7>(R.w1, ystV, 7 * h);
    if (!h) a += R.w1t * t;
    a += __shfl_xor(a, 1);
    if (!h) x1s[j1] = (f16)tanh_f(a + R.b1);
    if (tid < 304){
      int s = tid & 15;
      float a2 = (s == 0) ? R.w1tb * t : 0.f;
      const f16x2* yv2 = (const f16x2*)ystV + 4 * s;
#pragma unroll
      for (int p = 0; p < 4; p++) a2 = fdot2v(R.w1b[p], yv2[p], a2);
      a2 += __shfl_xor(a2, 1); a2 += __shfl_xor(a2, 2);
      a2 += __shfl_xor(a2, 4); a2 += __shfl_xor(a2, 8);
      if (s == 0) x1s[256 + (tid >> 4)] = (f16)tanh_f(a2 + R.b1b);
    }
  }
  __syncthreads();
  // ---- stage 2: x2 = tanh(x1 @ fW2^T + fb2), N=275, K=275 ----
  {
    float a = dot_chunks<18>(R.w2, x1V, 18 * h);
    a += __shfl_xor(a, 1);
    if (!h) x2s[j1] = (f16)tanh_f(a + R.b2);
    if (tid < 304){
      int s = tid & 15;
      float a2 = 0.f;
      const f16x2* xv2 = (const f16x2*)x1V + 9 * s;
#pragma unroll
      for (int p = 0; p < 9; p++) a2 = fdot2v(R.w2b[p], xv2[p], a2);
      a2 += __shfl_xor(a2, 1); a2 += __shfl_xor(a2, 2);
      a2 += __shfl_xor(a2, 4); a2 += __shfl_xor(a2, 8);
      if (s == 0) x2s[256 + (tid >> 4)] = (f16)tanh_f(a2 + R.b2b);
    }
  }
  __syncthreads();
  // ---- stage 3: f = tanh(x2 @ fW3^T + fb3), N=100, K=275 ----
  float a;
  {
    int q = tid & 3;
    a = dot_chunks<9>(R.w3, x2V, 9 * q);
    a += __shfl_xor(a, 1); a += __shfl_xor(a, 2);
  }
  return a + R.b3;
}

// ===================== Kernel 1: encoder + latent MLP =====================
__global__ __launch_bounds__(512) void k_encode(
    const float* __restrict__ past, const float* __restrict__ h0,
    const float* __restrict__ fW1, const float* __restrict__ fb1,
    const float* __restrict__ fW2, const float* __restrict__ fb2,
    const float* __restrict__ fW3, const float* __restrict__ fb3,
    const float* __restrict__ Wih, const float* __restrict__ Whh,
    const float* __restrict__ bih, const float* __restrict__ bhh,
    const float* __restrict__ gW1, const float* __restrict__ gb1,
    const float* __restrict__ gW2, const float* __restrict__ gb2,
    const float* __restrict__ gW3, const float* __restrict__ gb3,
    float* __restrict__ gx_ws)
{
  __shared__ f16x8 ystV[16];     // y staged (f16), pads zero
  __shared__ f16x8 x1V[36];      // 288 f16, pads zero
  __shared__ f16x8 x2V[36];
  __shared__ float yf[100];      // fp32 master state
  __shared__ float ghs[300];
  __shared__ f16x2 gW1s[75 * 52];
  __shared__ f16x2 gW2s[75 * 40];
  __shared__ f16x2 gW3s[80];
  __shared__ f16x2 g1s2[40];
  __shared__ f16x2 g2s2[40];

  const int tid = threadIdx.x;
  const int b = blockIdx.x;
  f16* yst = (f16*)ystV;
  f16* x1s = (f16*)x1V;
  f16* x2s = (f16*)x2V;
  f16* g1s = (f16*)g1s2;
  f16* g2s = (f16*)g2s2;

  FR R;
  load_field_regs(R, tid, fW1, fb1, fW2, fb2, fW3, fb3);

  // GRU hidden-hidden: pass1 rows 0..255 (2-way chunked), pass2 rows 256..299 (8-way)
  f16x2 whh[28]; float bhhv;
  f16x2 whhb[7]; float bhhbv;
  {
    int j1 = tid >> 1, h = tid & 1;
    ld_pairs<28>(Whh, j1, 100, 56 * h, whh, true);
    bhhv = bhh[j1];
    bool p2 = tid < 352;
    int j2 = 256 + (tid >> 3), s7 = tid & 7;
    ld_pairs<7>(Whh, p2 ? j2 : 0, 100, 14 * s7, whhb, p2);
    bhhbv = p2 ? bhh[j2] : 0.f;
  }
  float wihr=0,wihz=0,wihn=0,bihr=0,bihz=0,bihn=0;
  if (tid < 100){
    wihr = Wih[tid];       bihr = bih[tid];
    wihz = Wih[tid + 100]; bihz = bih[tid + 100];
    wihn = Wih[tid + 200]; bihn = bih[tid + 200];
  }
  const int jq = tid >> 2, qq = tid & 3;
  const bool lv = (qq == 0 && jq < 75);
  float gb1v = lv ? gb1[jq] : 0.f;
  float gb2v = lv ? gb2[jq] : 0.f;

  // latent weights -> LDS (f16, padded strides; used once)
  for (int i = tid; i < 75 * 52; i += 512){
    int r = i / 52, c = 2 * (i % 52);
    f16x2 v;
    v.x = (c     < 100) ? (f16)gW1[r * 100 + c]     : (f16)0.f;
    v.y = (c + 1 < 100) ? (f16)gW1[r * 100 + c + 1] : (f16)0.f;
    gW1s[i] = v;
  }
  for (int i = tid; i < 75 * 40; i += 512){
    int r = i / 40, c = 2 * (i % 40);
    f16x2 v;
    v.x = (c     < 75) ? (f16)gW2[r * 75 + c]     : (f16)0.f;
    v.y = (c + 1 < 75) ? (f16)gW2[r * 75 + c + 1] : (f16)0.f;
    gW2s[i] = v;
  }
  for (int i = tid; i < 80; i += 512){
    int r = i / 40, c = 2 * (i % 40);
    f16x2 v;
    v.x = (c     < 75) ? (f16)gW3[r * 75 + c]     : (f16)0.f;
    v.y = (c + 1 < 75) ? (f16)gW3[r * 75 + c + 1] : (f16)0.f;
    gW3s[i] = v;
  }
  // staging init (pads must be zero)
  for (int i = tid; i < 128; i += 512) yst[i] = (f16)0.f;
  for (int i = tid; i < 288; i += 512){ x1s[i] = (f16)0.f; x2s[i] = (f16)0.f; }
  for (int i = tid; i < 80;  i += 512){ g1s[i] = (f16)0.f; g2s[i] = (f16)0.f; }
  if (tid < 100){ float v = h0[b * 100 + tid]; yf[tid] = v; yst[tid] = (f16)v; }
  __syncthreads();

  const int j3 = tid >> 2;
  const bool wr3 = ((tid & 3) == 0) && (j3 < 100);
  float k1v = 0.f, k2v = 0.f, k3v = 0.f;

  auto rk_interval = [&](float tp, float tc){
    float dts = (tc - tp) * 0.5f;   // (t1-t0)/NSUB
#pragma unroll 1
    for (int sub = 0; sub < 2; sub++){
      float t0 = tp + sub * dts;
      __syncthreads();
      float a = field_eval(R, t0, tid, ystV, x1V, x2V, x1s, x2s);
      if (wr3){ float kv = tanh_f(a); k1v = kv; yst[j3] = (f16)(yf[j3] + 0.5f * dts * kv); }
      __syncthreads();
      a = field_eval(R, t0 + 0.5f * dts, tid, ystV, x1V, x2V, x1s, x2s);
      if (wr3){ float kv = tanh_f(a); k2v = kv; yst[j3] = (f16)(yf[j3] + 0.5f * dts * kv); }
      __syncthreads();
      a = field_eval(R, t0 + 0.5f * dts, tid, ystV, x1V, x2V, x1s, x2s);
      if (wr3){ float kv = tanh_f(a); k3v = kv; yst[j3] = (f16)(yf[j3] + dts * kv); }
      __syncthreads();
      a = field_eval(R, t0 + dts, tid, ystV, x1V, x2V, x1s, x2s);
      if (wr3){
        float kv = tanh_f(a);
        float yn = yf[j3] + dts * (k1v + 2.f * (k2v + k3v) + kv) * (1.f / 6.f);
        yf[j3] = yn; yst[j3] = (f16)yn;
      }
    }
  };

  const float* prow = past + b * 64;  // (32 steps) x [t, x]
#pragma unroll 1
  for (int st = 0; st < 32; st++){
    float tc = prow[2 * st];
    float tp = (st == 0) ? (tc - 1.f) : prow[2 * st - 2];
    rk_interval(tp, tc);
    // ---- GRU update ----
    __syncthreads();   // yst = integrated h ready
    {
      int j1 = tid >> 1, h = tid & 1;
      float a = dot_chunks<7>(whh, ystV, 7 * h);
      a += __shfl_xor(a, 1);
      if (!h) ghs[j1] = a + bhhv;
      if (tid < 352){
        int s7 = tid & 7;
        float a2 = 0.f;
        const f16x2* yv2 = (const f16x2*)ystV + 7 * s7;
#pragma unroll
        for (int p = 0; p < 7; p++) a2 = fdot2v(whhb[p], yv2[p], a2);
        a2 += __shfl_xor(a2, 1); a2 += __shfl_xor(a2, 2); a2 += __shfl_xor(a2, 4);
        if (s7 == 0) ghs[256 + (tid >> 3)] = a2 + bhhbv;
      }
    }
    __syncthreads();
    if (tid < 100){
      float x = prow[2 * st + 1];
      float r = sigm_f(x * wihr + bihr + ghs[tid]);
      float z = sigm_f(x * wihz + bihz + ghs[tid + 100]);
      float n = tanh_f(x * wihn + bihn + r * ghs[tid + 200]);
      float hn = (1.f - z) * n + z * yf[tid];
      yf[tid] = hn; yst[tid] = (f16)hn;
    }
  }

  // ---- latent MLP: gx = (leaky,leaky,linear)(h) ----
  __syncthreads();
  {
    float a = 0.f;
    const f16x2* yv = (const f16x2*)ystV + 13 * qq;
    if (jq < 75){
#pragma unroll
      for (int p = 0; p < 13; p++) a = fdot2v(gW1s[jq * 52 + 13 * qq + p], yv[p], a);
    }
    a += __shfl_xor(a, 1); a += __shfl_xor(a, 2);
    if (lv) g1s[jq] = (f16)leaky_f(a + gb1v);
  }
  __syncthreads();
  {
    float a = 0.f;
    const f16x2* xv = (const f16x2*)g1s + 10 * qq;
    if (jq < 75){
#pragma unroll
      for (int p = 0; p < 10; p++) a = fdot2v(gW2s[jq * 40 + 10 * qq + p], xv[p], a);
    }
    a += __shfl_xor(a, 1); a += __shfl_xor(a, 2);
    if (lv) g2s[jq] = (f16)leaky_f(a + gb2v);
  }
  __syncthreads();
  if (tid < 2){
    const f16x2* g2v = (const f16x2*)g2s;
    float a = gb3[tid];
    for (int p = 0; p < 40; p++) a = fdot2v(gW3s[tid * 40 + p], g2v[p], a);
    gx_ws[b * 2 + tid] = a;
  }
}

// ===================== Kernel 2: z0 + forecast ODE + decoder =====================
__global__ __launch_bounds__(512) void k_forecast(
    const float* __restrict__ t_future, const float* __restrict__ eps,
    const float* __restrict__ fW1, const float* __restrict__ fb1,
    const float* __restrict__ fW2, const float* __restrict__ fb2,
    const float* __restrict__ fW3, const float* __restrict__ fb3,
    const float* __restrict__ oW1, const float* __restrict__ ob1,
    const float* __restrict__ oW2, const float* __restrict__ ob2,
    const float* __restrict__ oW3, const float* __restrict__ ob3,
    const float* __restrict__ gx_ws, float* __restrict__ out)
{
  __shared__ f16x8 ystV[16];
  __shared__ f16x8 x1V[36];
  __shared__ f16x8 x2V[36];
  __shared__ float yf[100];
  __shared__ f16x8 o1V[12];      // 96 f16, pads zero
  __shared__ f16x8 o2V[12];

  const int tid = threadIdx.x;
  const int b = blockIdx.x;
  f16* yst = (f16*)ystV;
  f16* x1s = (f16*)x1V;
  f16* x2s = (f16*)x2V;
  f16* o1s = (f16*)o1V;
  f16* o2s = (f16*)o2V;

  FR R;
  load_field_regs(R, tid, fW1, fb1, fW2, fb2, fW3, fb3);

  // Decoder weights in registers:
  //  stage1: jq=tid>>2 (<75), qq: elements 32qq..32qq+31 of y (col = el), 4 chunks
  //  stage2: elements 24qq..24qq+23 of o1, 3 chunks
  //  stage3: tid<40: one f16x2 of oW3
  const int jq = tid >> 2, qq = tid & 3;
  const bool dv = jq < 75;
  const bool lv = (qq == 0 && dv);
  f16x2 dW1[16]; f16x2 dW2[12]; f16x2 dW3;
  ld_pairs<16>(oW1, dv ? jq : 0, 100, 32 * qq, dW1, dv);
  ld_pairs<12>(oW2, dv ? jq : 0, 75, 24 * qq, dW2, dv);
  ld_pairs<1>(oW3, 0, 75, 2 * tid, &dW3, tid < 40);
  float ob1v = lv ? ob1[jq] : 0.f;
  float ob2v = lv ? ob2[jq] : 0.f;
  float ob3v = ob3[0];

  for (int i = tid; i < 128; i += 512) yst[i] = (f16)0.f;
  for (int i = tid; i < 288; i += 512){ x1s[i] = (f16)0.f; x2s[i] = (f16)0.f; }
  for (int i = tid; i < 96;  i += 512){ o1s[i] = (f16)0.f; o2s[i] = (f16)0.f; }
  // z0 = loc + scale * eps  (pr reshuffle across rows via gx_ws)
  if (tid < 100){
    float loc, scl;
    if (b < 128){ loc = gx_ws[4 * b];          scl = gx_ws[4 * b + 2]; }
    else        { loc = fabsf(gx_ws[4 * b - 511]); scl = fabsf(gx_ws[4 * b - 509]); }
    float e = eps[tid * 256 + b];
    float v0 = loc + scl * e;
    yf[tid] = v0; yst[tid] = (f16)v0;
  }
  __syncthreads();

  auto decode = [&](int tf){
    // assumes a barrier has been passed and yst holds current y
    {
      float a = 0.f;
      if (dv) a = dot_chunks<4>(dW1, ystV, 4 * qq);
      a += __shfl_xor(a, 1); a += __shfl_xor(a, 2);
      if (lv) o1s[jq] = (f16)leaky_f(a + ob1v);
    }
    __syncthreads();
    {
      float a = 0.f;
      if (dv) a = dot_chunks<3>(dW2, o1V, 3 * qq);
      a += __shfl_xor(a, 1); a += __shfl_xor(a, 2);
      if (lv) o2s[jq] = (f16)leaky_f(a + ob2v);
    }
    __syncthreads();
    if (tid < 64){
      float a = 0.f;
      if (tid < 40) a = fdot2v(dW3, ((const f16x2*)o2V)[tid], 0.f);
      a += __shfl_xor(a, 1);  a += __shfl_xor(a, 2);  a += __shfl_xor(a, 4);
      a += __shfl_xor(a, 8);  a += __shfl_xor(a, 16); a += __shfl_xor(a, 32);
      if (tid == 0) out[b * 256 + tf] = a + ob3v;
    }
  };

  decode(0);

  const float* trow = t_future + b * 256;
  const int j3 = tid >> 2;
  const bool wr3 = ((tid & 3) == 0) && (j3 < 100);
  float k1v = 0.f, k2v = 0.f, k3v = 0.f;

#pragma unroll 1
  for (int iv = 0; iv < 255; iv++){
    float tp = trow[iv];
    float tc = trow[iv + 1];
    float dts = (tc - tp) * 0.5f;
#pragma unroll 1
    for (int sub = 0; sub < 2; sub++){
      float t0 = tp + sub * dts;
      __syncthreads();
      float a = field_eval(R, t0, tid, ystV, x1V, x2V, x1s, x2s);
      if (wr3){ float kv = tanh_f(a); k1v = kv; yst[j3] = (f16)(yf[j3] + 0.5f * dts * kv); }
      __syncthreads();
      a = field_eval(R, t0 + 0.5f * dts, tid, ystV, x1V, x2V, x1s, x2s);
      if (wr3){ float kv = tanh_f(a); k2v = kv; yst[j3] = (f16)(yf[j3] + 0.5f * dts * kv); }
      __syncthreads();
      a = field_eval(R, t0 + 0.5f * dts, tid, ystV, x1V, x2V, x1s, x2s);
      if (wr3){ float kv = tanh_f(a); k3v = kv; yst[j3] = (f16)(yf[j3] + dts * kv); }
      __syncthreads();
      a = field_eval(R, t0 + dts, tid, ystV, x1V, x2V, x1s, x2s);
      if (wr3){
        float kv = tanh_f(a);
        float yn = yf[j3] + dts * (k1v + 2.f * (k2v + k3v) + kv) * (1.f / 6.f);
        yf[j3] = yn; yst[j3] = (f16)yn;
      }
    }
    __syncthreads();   // yst ready for decoder
    decode(iv + 1);
  }
}

extern "C" void kernel_launch(void* const* d_in, const int* in_sizes, int n_in,
                              void* d_out, int out_size, void* d_ws, size_t ws_size,
                              hipStream_t stream) {
  (void)in_sizes; (void)n_in; (void)out_size; (void)ws_size;
  const float* past     = (const float*)d_in[0];
  const float* h0       = (const float*)d_in[1];
  const float* t_future = (const float*)d_in[2];
  const float* eps      = (const float*)d_in[3];
  const float* fW1 = (const float*)d_in[4];  const float* fb1 = (const float*)d_in[5];
  const float* fW2 = (const float*)d_in[6];  const float* fb2 = (const float*)d_in[7];
  const float* fW3 = (const float*)d_in[8];  const float* fb3 = (const float*)d_in[9];
  const float* Wih = (const float*)d_in[10]; const float* Whh = (const float*)d_in[11];
  const float* bih = (const float*)d_in[12]; const float* bhh = (const float*)d_in[13];
  const float* gW1 = (const float*)d_in[14]; const float* gb1 = (const float*)d_in[15];
  const float* gW2 = (const float*)d_in[16]; const float* gb2 = (const float*)d_in[17];
  const float* gW3 = (const float*)d_in[18]; const float* gb3 = (const float*)d_in[19];
  const float* oW1 = (const float*)d_in[20]; const float* ob1 = (const float*)d_in[21];
  const float* oW2 = (const float*)d_in[22]; const float* ob2 = (const float*)d_in[23];
  const float* oW3 = (const float*)d_in[24]; const float* ob3 = (const float*)d_in[25];
  float* gxws = (float*)d_ws;
  float* out = (float*)d_out;

  hipLaunchKernelGGL(k_encode, dim3(256), dim3(512), 0, stream,
      past, h0, fW1, fb1, fW2, fb2, fW3, fb3,
      Wih, Whh, bih, bhh, gW1, gb1, gW2, gb2, gW3, gb3, gxws);
  hipLaunchKernelGGL(k_forecast, dim3(256), dim3(512), 0, stream,
      t_future, eps, fW1, fb1, fW2, fb2, fW3, fb3,
      oW1, ob1, oW2, ob2, oW3, ob3, gxws, out);
}